// Round 1
// baseline (169.400 us; speedup 1.0000x reference)
//
#include <hip/hip_runtime.h>

typedef unsigned short u16;
typedef unsigned int u32;

typedef __bf16 bf16x8 __attribute__((ext_vector_type(8)));
typedef float floatx4 __attribute__((ext_vector_type(4)));

// ---- helpers ----------------------------------------------------------------

__device__ __forceinline__ u32 f2bf(float f) {
    // round-to-nearest-even fp32 -> bf16 (bit pattern in low 16)
    u32 u = __builtin_bit_cast(u32, f);
    return (u + 0x7fffu + ((u >> 16) & 1u)) >> 16;
}

__device__ __forceinline__ float quant_w(float x) {
    // WAGE Quantize.W, BITS_W=2: clip to [-0.5,0.5], round to grid step 0.5 (RNE)
    float xc = fminf(fmaxf(x, -0.5f), 0.5f);
    return rintf(xc * 2.0f) * 0.5f;
}

__device__ __forceinline__ void gload_lds16(const u16* g, u16* l) {
    __builtin_amdgcn_global_load_lds(
        (const __attribute__((address_space(1))) void*)g,
        (__attribute__((address_space(3))) void*)l,
        16, 0, 0);
}

// ---- kernel 1: cast A fp32 -> bf16 (8 floats / thread) ----------------------

__global__ __launch_bounds__(256) void cast_a_kernel(const float4* __restrict__ in,
                                                     uint4* __restrict__ out) {
    int t = blockIdx.x * 256 + threadIdx.x;
    float4 a = in[2 * t];
    float4 b = in[2 * t + 1];
    uint4 o;
    o.x = f2bf(a.x) | (f2bf(a.y) << 16);
    o.y = f2bf(a.z) | (f2bf(a.w) << 16);
    o.z = f2bf(b.x) | (f2bf(b.y) << 16);
    o.w = f2bf(b.z) | (f2bf(b.w) << 16);
    out[t] = o;
}

// ---- kernel 2: quantize + transpose W[k][n] -> Bt[n][k] bf16 ----------------

__global__ __launch_bounds__(256) void quant_transpose_kernel(const float* __restrict__ W,
                                                              u16* __restrict__ Bt) {
    __shared__ u16 tile[32][33];  // +1 pad: no bank conflicts
    const int KN = 1024;
    int tx = threadIdx.x;  // 0..31
    int ty = threadIdx.y;  // 0..7
    int k0 = blockIdx.y * 32;
    int n0 = blockIdx.x * 32;
#pragma unroll
    for (int i = 0; i < 4; i++) {
        int kl = ty + i * 8;
        float x = W[(k0 + kl) * KN + n0 + tx];
        tile[kl][tx] = (u16)f2bf(quant_w(x));
    }
    __syncthreads();
#pragma unroll
    for (int i = 0; i < 4; i++) {
        int nl = ty + i * 8;
        Bt[(n0 + nl) * KN + k0 + tx] = tile[tx][nl];
    }
}

// ---- kernel 3: C[M][N] = A[M][K] * Bt[N][K]^T  (bf16 MFMA, fp32 out) --------
// m97 structure: 128x128 tile, BK=32, global_load_lds dwordx4 staging,
// 4 waves in 2x2 grid, 4x4 16x16 acc tiles per wave.

__global__ __launch_bounds__(256) void gemm_bt_kernel(const u16* __restrict__ A,
                                                      const u16* __restrict__ Bt,
                                                      float* __restrict__ C) {
    const int K = 1024;
    const int N = 1024;

    __shared__ alignas(16) u16 As[128 * 32];
    __shared__ alignas(16) u16 Bs[128 * 32];

    const int tid = threadIdx.x;
    const int mbase = blockIdx.y * 128;
    const int nbase = blockIdx.x * 128;
    const int lane = tid & 63;
    const int wv = tid >> 6;
    const int wm = (wv & 1) * 64;
    const int wn = (wv >> 1) * 64;
    const int frow = lane & 15;           // m (or n) index within 16-tile
    const int fk = (lane >> 4) * 8;       // k offset within BK=32

    floatx4 acc[4][4] = {};

    // staging addresses: chunk c (0..511) covers row c>>2, k-chunk (c&3)*8
    const u16* Ag0 = &A[(mbase + (tid >> 2)) * K + (tid & 3) * 8];
    const u16* Ag1 = Ag0 + 64 * K;
    const u16* Bg0 = &Bt[(nbase + (tid >> 2)) * K + (tid & 3) * 8];
    const u16* Bg1 = Bg0 + 64 * K;
    u16* la0 = &As[tid * 8];
    u16* la1 = &As[(tid + 256) * 8];
    u16* lb0 = &Bs[tid * 8];
    u16* lb1 = &Bs[(tid + 256) * 8];

    for (int kt = 0; kt < K; kt += 32) {
        __syncthreads();  // prior iteration's LDS reads done before overwrite
        gload_lds16(Ag0 + kt, la0);
        gload_lds16(Ag1 + kt, la1);
        gload_lds16(Bg0 + kt, lb0);
        gload_lds16(Bg1 + kt, lb1);
        __syncthreads();  // compiler emits vmcnt(0) drain before barrier

        bf16x8 af[4], bf[4];
#pragma unroll
        for (int i = 0; i < 4; i++)
            af[i] = *(const bf16x8*)&As[(wm + i * 16 + frow) * 32 + fk];
#pragma unroll
        for (int j = 0; j < 4; j++)
            bf[j] = *(const bf16x8*)&Bs[(wn + j * 16 + frow) * 32 + fk];
#pragma unroll
        for (int i = 0; i < 4; i++)
#pragma unroll
            for (int j = 0; j < 4; j++)
                acc[i][j] = __builtin_amdgcn_mfma_f32_16x16x32_bf16(
                    af[i], bf[j], acc[i][j], 0, 0, 0);
    }

    // epilogue: C/D layout col = lane&15, row = (lane>>4)*4 + reg
    const int crow = (lane >> 4) * 4;
    const int ccol = lane & 15;
#pragma unroll
    for (int i = 0; i < 4; i++) {
#pragma unroll
        for (int j = 0; j < 4; j++) {
            float* cp = &C[(mbase + wm + i * 16 + crow) * N + nbase + wn + j * 16 + ccol];
#pragma unroll
            for (int r = 0; r < 4; r++) cp[r * N] = acc[i][j][r];
        }
    }
}

// ---- launch -----------------------------------------------------------------

extern "C" void kernel_launch(void* const* d_in, const int* in_sizes, int n_in,
                              void* d_out, int out_size, void* d_ws, size_t ws_size,
                              hipStream_t stream) {
    const float* A = (const float*)d_in[0];   // 16384 x 1024
    const float* W = (const float*)d_in[1];   // 1024 x 1024
    float* C = (float*)d_out;                 // 16384 x 1024

    u16* Abf = (u16*)d_ws;                                   // 32 MB
    u16* Btq = (u16*)((char*)d_ws + (size_t)33554432);       // 2 MB

    // 16384*1024 floats / 8 per thread = 2097152 threads
    cast_a_kernel<<<8192, 256, 0, stream>>>((const float4*)A, (uint4*)Abf);
    quant_transpose_kernel<<<dim3(32, 32), dim3(32, 8), 0, stream>>>(W, Btq);
    gemm_bt_kernel<<<dim3(8, 128), 256, 0, stream>>>(Abf, Btq, C);
}

// Round 2
// 151.846 us; speedup vs baseline: 1.1156x; 1.1156x over previous
//
#include <hip/hip_runtime.h>

typedef unsigned short u16;
typedef unsigned int u32;

typedef __bf16 bf16x8 __attribute__((ext_vector_type(8)));
typedef float floatx4 __attribute__((ext_vector_type(4)));

// ---- helpers ----------------------------------------------------------------

__device__ __forceinline__ u32 f2bf(float f) {
    // round-to-nearest-even fp32 -> bf16 (bit pattern in low 16)
    u32 u = __builtin_bit_cast(u32, f);
    return (u + 0x7fffu + ((u >> 16) & 1u)) >> 16;
}

__device__ __forceinline__ float quant_w(float x) {
    // WAGE Quantize.W, BITS_W=2: clip to [-0.5,0.5], round to grid step 0.5 (RNE)
    float xc = fminf(fmaxf(x, -0.5f), 0.5f);
    return rintf(xc * 2.0f) * 0.5f;
}

__device__ __forceinline__ void gload_lds16(const u16* g, u16* l) {
    __builtin_amdgcn_global_load_lds(
        (const __attribute__((address_space(1))) void*)g,
        (__attribute__((address_space(3))) void*)l,
        16, 0, 0);
}

// ---- kernel 1: cast A fp32 -> bf16 (8 floats / thread) ----------------------

__global__ __launch_bounds__(256) void cast_a_kernel(const float4* __restrict__ in,
                                                     uint4* __restrict__ out) {
    int t = blockIdx.x * 256 + threadIdx.x;
    float4 a = in[2 * t];
    float4 b = in[2 * t + 1];
    uint4 o;
    o.x = f2bf(a.x) | (f2bf(a.y) << 16);
    o.y = f2bf(a.z) | (f2bf(a.w) << 16);
    o.z = f2bf(b.x) | (f2bf(b.y) << 16);
    o.w = f2bf(b.z) | (f2bf(b.w) << 16);
    out[t] = o;
}

// ---- kernel 2: quantize + transpose W[k][n] -> Bt[n][k] bf16 ----------------

__global__ __launch_bounds__(256) void quant_transpose_kernel(const float* __restrict__ W,
                                                              u16* __restrict__ Bt) {
    __shared__ u16 tile[32][33];  // +1 pad: no bank conflicts
    const int KN = 1024;
    int tx = threadIdx.x;  // 0..31
    int ty = threadIdx.y;  // 0..7
    int k0 = blockIdx.y * 32;
    int n0 = blockIdx.x * 32;
#pragma unroll
    for (int i = 0; i < 4; i++) {
        int kl = ty + i * 8;
        float x = W[(k0 + kl) * KN + n0 + tx];
        tile[kl][tx] = (u16)f2bf(quant_w(x));
    }
    __syncthreads();
#pragma unroll
    for (int i = 0; i < 4; i++) {
        int nl = ty + i * 8;
        Bt[(n0 + nl) * KN + k0 + tx] = tile[tx][nl];
    }
}

// ---- kernel 3: C[M][N] = A[M][K] * Bt[N][K]^T  (bf16 MFMA, fp32 out) --------
// 128x128 tile, BK=64 (32 MFMA / barrier), global_load_lds dwordx4 staging,
// XOR bank-swizzle on k-chunks, grid x = M-blocks for per-XCD L2 locality.

__global__ __launch_bounds__(256) void gemm_bt_kernel(const u16* __restrict__ A,
                                                      const u16* __restrict__ Bt,
                                                      float* __restrict__ C) {
    const int K = 1024;
    const int N = 1024;

    __shared__ alignas(16) u16 As[128 * 64];  // 16 KB
    __shared__ alignas(16) u16 Bs[128 * 64];  // 16 KB

    const int tid = threadIdx.x;
    const int mbase = blockIdx.x * 128;   // x = M so XCD (id%8) sees 16 rows x 8 cols
    const int nbase = blockIdx.y * 128;
    const int lane = tid & 63;
    const int wv = tid >> 6;
    const int wm = (wv & 1) * 64;
    const int wn = (wv >> 1) * 64;
    const int frow = lane & 15;           // m (or n) index within 16-tile
    const int fkc = lane >> 4;            // k-chunk index within 32-wide k-step (0..3)
    const int rsw = frow & 7;             // XOR bank swizzle key

    floatx4 acc[4][4] = {};

    // staging: per call q (0..3), thread t stages chunk c = q*256+t:
    //   LDS (linear, DMA constraint): As[c*8 .. c*8+8)
    //   row = q*32 + (t>>3); global k-chunk g8 = (t&7) ^ (row&7)  [bank swizzle]
    const int srow = tid >> 3;
    const int g8 = (tid & 7) ^ (srow & 7);
    const u16* Aga[4];
    const u16* Bga[4];
#pragma unroll
    for (int q = 0; q < 4; q++) {
        Aga[q] = &A[(size_t)(mbase + q * 32 + srow) * K + g8 * 8];
        Bga[q] = &Bt[(size_t)(nbase + q * 32 + srow) * K + g8 * 8];
    }

    for (int kt = 0; kt < K; kt += 64) {
        __syncthreads();  // prior iteration's LDS reads done before overwrite
#pragma unroll
        for (int q = 0; q < 4; q++) {
            gload_lds16(Aga[q] + kt, &As[(q * 256 + tid) * 8]);
            gload_lds16(Bga[q] + kt, &Bs[(q * 256 + tid) * 8]);
        }
        __syncthreads();  // vmcnt(0) drain + barrier

#pragma unroll
        for (int s = 0; s < 2; s++) {
            bf16x8 af[4], bf[4];
#pragma unroll
            for (int i = 0; i < 4; i++)
                af[i] = *(const bf16x8*)&As[(wm + i * 16 + frow) * 64 +
                                            (((s * 4 + fkc) ^ rsw) * 8)];
#pragma unroll
            for (int j = 0; j < 4; j++)
                bf[j] = *(const bf16x8*)&Bs[(wn + j * 16 + frow) * 64 +
                                            (((s * 4 + fkc) ^ rsw) * 8)];
#pragma unroll
            for (int i = 0; i < 4; i++)
#pragma unroll
                for (int j = 0; j < 4; j++)
                    acc[i][j] = __builtin_amdgcn_mfma_f32_16x16x32_bf16(
                        af[i], bf[j], acc[i][j], 0, 0, 0);
        }
    }

    // epilogue: C/D layout col = lane&15, row = (lane>>4)*4 + reg
    const int crow = (lane >> 4) * 4;
    const int ccol = lane & 15;
#pragma unroll
    for (int i = 0; i < 4; i++) {
#pragma unroll
        for (int j = 0; j < 4; j++) {
            float* cp = &C[(size_t)(mbase + wm + i * 16 + crow) * N + nbase + wn + j * 16 + ccol];
#pragma unroll
            for (int r = 0; r < 4; r++) cp[r * N] = acc[i][j][r];
        }
    }
}

// ---- launch -----------------------------------------------------------------

extern "C" void kernel_launch(void* const* d_in, const int* in_sizes, int n_in,
                              void* d_out, int out_size, void* d_ws, size_t ws_size,
                              hipStream_t stream) {
    const float* A = (const float*)d_in[0];   // 16384 x 1024
    const float* W = (const float*)d_in[1];   // 1024 x 1024
    float* C = (float*)d_out;                 // 16384 x 1024

    u16* Abf = (u16*)d_ws;                                   // 32 MB
    u16* Btq = (u16*)((char*)d_ws + (size_t)33554432);       // 2 MB

    cast_a_kernel<<<8192, 256, 0, stream>>>((const float4*)A, (uint4*)Abf);
    quant_transpose_kernel<<<dim3(32, 32), dim3(32, 8), 0, stream>>>(W, Btq);
    gemm_bt_kernel<<<dim3(128, 8), 256, 0, stream>>>(Abf, Btq, C);
}